// Round 2
// baseline (886.769 us; speedup 1.0000x reference)
//
#include <hip/hip_runtime.h>
#include <math.h>

// Problem dims
constexpr int kH  = 1024;
constexpr int kV  = 50257;
constexpr int kS  = 4096;
constexpr int kH4 = kH / 4;    // 256 float4 per H row
constexpr int kH2 = 2 * kH;    // 2048

// Workspace layout (float offsets)
constexpr int WS_H0     = 0;       // 1024
constexpr int WS_GH1    = 1024;    // 3072
constexpr int WS_H1     = 4096;    // 1024
constexpr int WS_V      = 5120;    // 1024
constexpr int WS_CTX    = 6144;    // 1024
constexpr int WS_SC     = 7168;    // [0]=c
constexpr int WS_PM2    = 7184;    // 256 per-block maxes (kattn)
constexpr int WS_GS2    = 7440;    // 16 sum-exp cells (kattn)
constexpr int WS_PM8    = 7456;    // 256 per-block maxes (k8)
constexpr int WS_GS8    = 7712;    // 16 sum-exp cells (k8)
constexpr int WS_CNT    = 7728;    // [0]=kattn counter, [1]=k8 counter (int cells)
constexpr int WS_LOGITS = 7744;    // 50257  (7744 % 4 == 0 -> 16B aligned)

// d_out layout (floats): logits | context | hidden(h0,h1) | attn
constexpr int OUT_LOGITS = 0;
constexpr int OUT_CTX    = kV;                 // NOT 16B aligned -> scalar stores only
constexpr int OUT_HID    = kV + kH;
constexpr int OUT_ATTN   = kV + kH + 2 * kH;

__device__ __forceinline__ float wred_sum(float v) {
#pragma unroll
  for (int o = 32; o > 0; o >>= 1) v += __shfl_down(v, o, 64);
  return v;  // valid in lane 0
}
__device__ __forceinline__ float wred_max(float v) {
#pragma unroll
  for (int o = 32; o > 0; o >>= 1) v = fmaxf(v, __shfl_down(v, o, 64));
  return v;  // valid in lane 0
}
__device__ __forceinline__ float sigmoidf_(float x) { return 1.0f / (1.0f + __expf(-x)); }
__device__ __forceinline__ float dot4(float4 a, float4 b) {
  return a.x * b.x + a.y * b.y + a.z * b.z + a.w * b.w;
}

// Non-temporal float4 load (single-use weight streams)
typedef float f32x4_t __attribute__((ext_vector_type(4)));
__device__ __forceinline__ float4 ntld(const float4* p) {
  f32x4_t v = __builtin_nontemporal_load((const f32x4_t*)p);
  return make_float4(v.x, v.y, v.z, v.w);
}

// Manual grid sync. SAFE ONLY because every grid using it is <= 256 blocks of
// 256 threads with small VGPR/LDS -> all blocks co-resident on 256 CUs.
// Counter is zeroed by k2 every iteration (ws is re-poisoned between iters).
__device__ __forceinline__ void gsync(int* cnt, int target) {
  __syncthreads();
  __threadfence();
  if (threadIdx.x == 0) {
    atomicAdd(cnt, 1);
    while (__hip_atomic_load(cnt, __ATOMIC_RELAXED, __HIP_MEMORY_SCOPE_AGENT) < target) {
      __builtin_amdgcn_s_sleep(2);
    }
  }
  __syncthreads();
  __threadfence();
}

// K1: blocks [0,256): GRU0 -> h0 ; blocks [256,1024): gh1 = W_hh1 @ h_prev1 + b_hh1
__global__ void k1_gru0_gh1(const int* __restrict__ wi_p, const float* __restrict__ lc,
                            const float* __restrict__ lh, const float* __restrict__ emb,
                            const float* __restrict__ W_ih0, const float* __restrict__ W_hh0,
                            const float* __restrict__ b_ih0, const float* __restrict__ b_hh0,
                            const float* __restrict__ W_hh1, const float* __restrict__ b_hh1,
                            float* __restrict__ ws) {
  const int wave = threadIdx.x >> 6, lane = threadIdx.x & 63;
  const int b = blockIdx.x;
  if (b < 256) {
    const int j = b * 4 + wave;
    const int wi = wi_p[0];
    const float4* embr = (const float4*)(emb + (size_t)wi * kH);
    const float4* lc4  = (const float4*)lc;
    const float4* Wr = (const float4*)(W_ih0 + (size_t)j * kH2);
    const float4* Wz = (const float4*)(W_ih0 + (size_t)(j + kH) * kH2);
    const float4* Wn = (const float4*)(W_ih0 + (size_t)(j + 2 * kH) * kH2);
    float ar = 0.f, az = 0.f, an = 0.f;
#pragma unroll
    for (int i = 0; i < 8; i++) {
      const int idx = lane + i * 64;
      const float4 xv = (idx < kH4) ? embr[idx] : lc4[idx - kH4];
      ar += dot4(ntld(Wr + idx), xv);
      az += dot4(ntld(Wz + idx), xv);
      an += dot4(ntld(Wn + idx), xv);
    }
    const float4* Ur = (const float4*)(W_hh0 + (size_t)j * kH);
    const float4* Uz = (const float4*)(W_hh0 + (size_t)(j + kH) * kH);
    const float4* Un = (const float4*)(W_hh0 + (size_t)(j + 2 * kH) * kH);
    const float4* h4 = (const float4*)lh;
    float br = 0.f, bz = 0.f, bn = 0.f;
#pragma unroll
    for (int i = 0; i < 4; i++) {
      const int idx = lane + i * 64;
      const float4 hv = h4[idx];
      br += dot4(ntld(Ur + idx), hv);
      bz += dot4(ntld(Uz + idx), hv);
      bn += dot4(ntld(Un + idx), hv);
    }
    ar = wred_sum(ar); az = wred_sum(az); an = wred_sum(an);
    br = wred_sum(br); bz = wred_sum(bz); bn = wred_sum(bn);
    if (lane == 0) {
      const float r = sigmoidf_(ar + b_ih0[j] + br + b_hh0[j]);
      const float z = sigmoidf_(az + b_ih0[j + kH] + bz + b_hh0[j + kH]);
      const float n = tanhf(an + b_ih0[j + 2 * kH] + r * (bn + b_hh0[j + 2 * kH]));
      ws[WS_H0 + j] = (1.f - z) * n + z * lh[j];
    }
  } else {
    const int row = (b - 256) * 4 + wave;  // [0, 3072)
    const float4* W  = (const float4*)(W_hh1 + (size_t)row * kH);
    const float4* h4 = (const float4*)(lh + kH);
    float a = 0.f;
#pragma unroll
    for (int i = 0; i < 4; i++) {
      const int idx = lane + i * 64;
      a += dot4(ntld(W + idx), h4[idx]);
    }
    a = wred_sum(a);
    if (lane == 0) ws[WS_GH1 + row] = a + b_hh1[row];
  }
}

// K2: GRU1 -> h1 ; write hidden outputs ; zero all accumulators/counters for this iter
__global__ void k2_gru1(const float* __restrict__ lh, const float* __restrict__ W_ih1,
                        const float* __restrict__ b_ih1, float* __restrict__ ws,
                        float* __restrict__ out) {
  const int wave = threadIdx.x >> 6, lane = threadIdx.x & 63;
  const int t = threadIdx.x;
  const int j = blockIdx.x * 4 + wave;
  const float4* x4 = (const float4*)(ws + WS_H0);
  const float4* Wr = (const float4*)(W_ih1 + (size_t)j * kH);
  const float4* Wz = (const float4*)(W_ih1 + (size_t)(j + kH) * kH);
  const float4* Wn = (const float4*)(W_ih1 + (size_t)(j + 2 * kH) * kH);
  float ar = 0.f, az = 0.f, an = 0.f;
#pragma unroll
  for (int i = 0; i < 4; i++) {
    const int idx = lane + i * 64;
    const float4 xv = x4[idx];
    ar += dot4(ntld(Wr + idx), xv);
    az += dot4(ntld(Wz + idx), xv);
    an += dot4(ntld(Wn + idx), xv);
  }
  ar = wred_sum(ar); az = wred_sum(az); an = wred_sum(an);
  if (lane == 0) {
    const float r = sigmoidf_(ar + b_ih1[j] + ws[WS_GH1 + j]);
    const float z = sigmoidf_(az + b_ih1[j + kH] + ws[WS_GH1 + j + kH]);
    const float n = tanhf(an + b_ih1[j + 2 * kH] + r * ws[WS_GH1 + j + 2 * kH]);
    const float h1 = (1.f - z) * n + z * lh[kH + j];
    ws[WS_H1 + j] = h1;
    out[OUT_HID + kH + j] = h1;          // hidden[1]
    out[OUT_HID + j] = ws[WS_H0 + j];    // hidden[0]
  }
  // zero per-iteration accumulators (ws is re-poisoned between iterations)
  if (blockIdx.x < 4) {
    ws[WS_V + blockIdx.x * 256 + t] = 0.f;
  } else if (blockIdx.x < 8) {
    ws[WS_CTX + (blockIdx.x - 4) * 256 + t] = 0.f;
  } else if (blockIdx.x == 8) {
    if (t < 16) ws[WS_GS2 + t] = 0.f;
    else if (t >= 32 && t < 48) ws[WS_GS8 + (t - 32)] = 0.f;
    else if (t >= 64 && t < 66) ((int*)ws)[WS_CNT + (t - 64)] = 0;
  }
}

// KS1: logits[r] = W_out[r, :1024] . h1 + b_out[r]   (206 MB stream, 2 rows/wave)
__global__ void ks1_logits_h1(const float* __restrict__ W_out, const float* __restrict__ b_out,
                              float* __restrict__ ws) {
  const int wave = threadIdx.x >> 6, lane = threadIdx.x & 63;
  const int r0 = blockIdx.x * 8 + wave * 2;
  if (r0 >= kV) return;
  const int r1 = (r0 + 1 < kV) ? r0 + 1 : r0;
  const float4* A = (const float4*)(W_out + (size_t)r0 * kH2);
  const float4* B = (const float4*)(W_out + (size_t)r1 * kH2);
  const float4* x4 = (const float4*)(ws + WS_H1);
  float a0 = 0.f, a1 = 0.f;
#pragma unroll
  for (int i = 0; i < 4; i++) {
    const int idx = lane + i * 64;
    const float4 xv = x4[idx];
    a0 += dot4(ntld(A + idx), xv);
    a1 += dot4(ntld(B + idx), xv);
  }
  a0 = wred_sum(a0); a1 = wred_sum(a1);
  if (lane == 0) {
    ws[WS_LOGITS + r0] = a0 + b_out[r0];
    if (r1 != r0) ws[WS_LOGITS + r1] = a1 + b_out[r1];
  }
}

// KATTN: fused attention. 256 blocks x 256 threads, all co-resident.
// Phase V: v = W_attn.T @ h1 (atomic partials), block0 also c = b_attn.h1
// Phase E: energies for 16 rows/block (kept in LDS) + per-block max
// Phase S: global max -> unnormalized exp in LDS -> partial sums (16 cells)
// Phase C: normalize, context partials (enc rows L2-hot from phase E), attn out
__global__ void kattn_fused(const float* __restrict__ enc, const float* __restrict__ W_attn,
                            const float* __restrict__ b_attn, float* __restrict__ ws,
                            float* __restrict__ out) {
  __shared__ float lds_e[16];
  __shared__ float lds_u[16];
  __shared__ float redl[4];
  const int b = blockIdx.x, t = threadIdx.x;
  const int wave = t >> 6, lane = t & 63;
  int* cnt = ((int*)ws) + WS_CNT + 0;

  // ---- Phase V ----
  {
    const float4* W4 = (const float4*)W_attn;
    float4 acc = make_float4(0.f, 0.f, 0.f, 0.f);
    const int j0 = b * 4;
#pragma unroll
    for (int jj = 0; jj < 4; jj++) {
      const int j = j0 + jj;
      const float s = ws[WS_H1 + j];
      const float4 w = ntld(W4 + (size_t)j * kH4 + t);
      acc.x += s * w.x; acc.y += s * w.y; acc.z += s * w.z; acc.w += s * w.w;
    }
    atomicAdd(&ws[WS_V + 4 * t + 0], acc.x);
    atomicAdd(&ws[WS_V + 4 * t + 1], acc.y);
    atomicAdd(&ws[WS_V + 4 * t + 2], acc.z);
    atomicAdd(&ws[WS_V + 4 * t + 3], acc.w);
    if (b == 0) {
      float a = 0.f;
      for (int i = t; i < kH; i += 256) a += b_attn[i] * ws[WS_H1 + i];
      a = wred_sum(a);
      if (lane == 0) redl[wave] = a;
      __syncthreads();
      if (t == 0) ws[WS_SC + 0] = redl[0] + redl[1] + redl[2] + redl[3];
    }
  }
  gsync(cnt, 256);

  // ---- Phase E ----  (16 rows per block, 4 per wave, pairs for MLP)
  {
    const float4* v4 = (const float4*)(ws + WS_V);
    const float cc = ws[WS_SC + 0];
    const int sbase = b * 16 + wave * 4;
#pragma unroll
    for (int rr = 0; rr < 4; rr += 2) {
      const int s = sbase + rr;
      const float4* ea = (const float4*)(enc + (size_t)s * kH);
      const float4* eb = ea + kH4;
      float a0 = 0.f, a1 = 0.f;
#pragma unroll
      for (int i = 0; i < 4; i++) {
        const int idx = lane + i * 64;
        const float4 vv = v4[idx];
        a0 += dot4(ea[idx], vv);
        a1 += dot4(eb[idx], vv);
      }
      a0 = wred_sum(a0); a1 = wred_sum(a1);
      if (lane == 0) {
        lds_e[wave * 4 + rr]     = a0 + cc;
        lds_e[wave * 4 + rr + 1] = a1 + cc;
      }
    }
    __syncthreads();
    if (t == 0) {
      float m = lds_e[0];
#pragma unroll
      for (int i = 1; i < 16; i++) m = fmaxf(m, lds_e[i]);
      ws[WS_PM2 + b] = m;
    }
  }
  gsync(cnt, 512);

  // ---- Phase S ----
  float gm;
  {
    float pm = ws[WS_PM2 + t];  // exactly 256 cells
    float wm = wred_max(pm);
    if (lane == 0) redl[wave] = wm;
    __syncthreads();
    gm = fmaxf(fmaxf(redl[0], redl[1]), fmaxf(redl[2], redl[3]));
    __syncthreads();
    if (t < 16) lds_u[t] = __expf(lds_e[t] - gm);
    __syncthreads();
    if (t == 0) {
      float s16 = 0.f;
#pragma unroll
      for (int i = 0; i < 16; i++) s16 += lds_u[i];
      atomicAdd(&ws[WS_GS2 + (b & 15)], s16);
    }
  }
  gsync(cnt, 768);

  // ---- Phase C ----
  {
    if (t < 16) lds_e[t] = ws[WS_GS2 + t];  // reuse lds_e as scratch
    __syncthreads();
    float tot = 0.f;
#pragma unroll
    for (int i = 0; i < 16; i++) tot += lds_e[i];
    const float inv = 1.0f / tot;
    const float4* e4 = (const float4*)enc;
    float4 acc = make_float4(0.f, 0.f, 0.f, 0.f);
    const int s0 = b * 16;
#pragma unroll
    for (int ss = 0; ss < 16; ss++) {
      const int s = s0 + ss;
      const float a = lds_u[ss] * inv;
      const float4 ev = e4[(size_t)s * kH4 + t];  // L2-hot from phase E
      acc.x += a * ev.x; acc.y += a * ev.y; acc.z += a * ev.z; acc.w += a * ev.w;
    }
    atomicAdd(&ws[WS_CTX + 4 * t + 0], acc.x);
    atomicAdd(&ws[WS_CTX + 4 * t + 1], acc.y);
    atomicAdd(&ws[WS_CTX + 4 * t + 2], acc.z);
    atomicAdd(&ws[WS_CTX + 4 * t + 3], acc.w);
    if (t < 16) out[OUT_ATTN + s0 + t] = lds_u[t] * inv;
  }
}

// KS2: logits[r] += W_out[r, 1024:] . ctx   (other 206 MB stream, 2 rows/wave)
__global__ void ks2_logits_ctx(const float* __restrict__ W_out, float* __restrict__ ws) {
  const int wave = threadIdx.x >> 6, lane = threadIdx.x & 63;
  const int r0 = blockIdx.x * 8 + wave * 2;
  if (r0 >= kV) return;
  const int r1 = (r0 + 1 < kV) ? r0 + 1 : r0;
  const float4* A = (const float4*)(W_out + (size_t)r0 * kH2 + kH);
  const float4* B = (const float4*)(W_out + (size_t)r1 * kH2 + kH);
  const float4* c4 = (const float4*)(ws + WS_CTX);
  float a0 = 0.f, a1 = 0.f;
#pragma unroll
  for (int i = 0; i < 4; i++) {
    const int idx = lane + i * 64;
    const float4 xv = c4[idx];
    a0 += dot4(ntld(A + idx), xv);
    a1 += dot4(ntld(B + idx), xv);
  }
  a0 = wred_sum(a0); a1 = wred_sum(a1);
  if (lane == 0) {
    ws[WS_LOGITS + r0] += a0;
    if (r1 != r0) ws[WS_LOGITS + r1] += a1;
  }
}

// K8: fused log-sum-exp + final writes. 197 blocks, each thread owns one logit.
__global__ void k8_lse_out(float* __restrict__ ws, float* __restrict__ out) {
  __shared__ float redl[4];
  __shared__ float lds16[16];
  const int b = blockIdx.x, t = threadIdx.x;
  const int wave = t >> 6, lane = t & 63;
  int* cnt = ((int*)ws) + WS_CNT + 1;
  const int g = b * 256 + t;
  const float x = (g < kV) ? ws[WS_LOGITS + g] : -INFINITY;
  // block max -> PM8
  {
    float m = wred_max(x);
    if (lane == 0) redl[wave] = m;
    __syncthreads();
    if (t == 0) ws[WS_PM8 + b] = fmaxf(fmaxf(redl[0], redl[1]), fmaxf(redl[2], redl[3]));
  }
  gsync(cnt, 197);
  // global max, partial sumexp
  float gm;
  {
    float pm = (t < 197) ? ws[WS_PM8 + t] : -INFINITY;
    float wm = wred_max(pm);
    if (lane == 0) redl[wave] = wm;
    __syncthreads();
    gm = fmaxf(fmaxf(redl[0], redl[1]), fmaxf(redl[2], redl[3]));
    __syncthreads();
    const float e = (g < kV) ? __expf(x - gm) : 0.f;
    float s = wred_sum(e);
    if (lane == 0) redl[wave] = s;
    __syncthreads();
    if (t == 0) atomicAdd(&ws[WS_GS8 + (b & 15)], redl[0] + redl[1] + redl[2] + redl[3]);
  }
  gsync(cnt, 394);
  // finalize
  {
    if (t < 16) lds16[t] = ws[WS_GS8 + t];
    __syncthreads();
    float tot = 0.f;
#pragma unroll
    for (int i = 0; i < 16; i++) tot += lds16[i];
    const float shift = gm + logf(tot);
    if (g < kV) out[OUT_LOGITS + g] = x - shift;
    if (g < kH) out[OUT_CTX + g] = ws[WS_CTX + g];
  }
}

extern "C" void kernel_launch(void* const* d_in, const int* in_sizes, int n_in,
                              void* d_out, int out_size, void* d_ws, size_t ws_size,
                              hipStream_t stream) {
  const int*   wi     = (const int*)d_in[0];
  const float* lc     = (const float*)d_in[1];
  const float* lh     = (const float*)d_in[2];
  const float* enc    = (const float*)d_in[3];
  const float* emb    = (const float*)d_in[4];
  const float* W_ih0  = (const float*)d_in[5];
  const float* W_hh0  = (const float*)d_in[6];
  const float* b_ih0  = (const float*)d_in[7];
  const float* b_hh0  = (const float*)d_in[8];
  const float* W_ih1  = (const float*)d_in[9];
  const float* W_hh1  = (const float*)d_in[10];
  const float* b_ih1  = (const float*)d_in[11];
  const float* b_hh1  = (const float*)d_in[12];
  const float* W_attn = (const float*)d_in[13];
  const float* b_attn = (const float*)d_in[14];
  const float* W_out  = (const float*)d_in[15];
  const float* b_out  = (const float*)d_in[16];
  float* out = (float*)d_out;
  float* ws  = (float*)d_ws;

  constexpr int kStreamBlocks = (kV + 7) / 8;  // 6283

  k1_gru0_gh1<<<1024, 256, 0, stream>>>(wi, lc, lh, emb, W_ih0, W_hh0, b_ih0, b_hh0,
                                        W_hh1, b_hh1, ws);
  k2_gru1<<<256, 256, 0, stream>>>(lh, W_ih1, b_ih1, ws, out);
  ks1_logits_h1<<<kStreamBlocks, 256, 0, stream>>>(W_out, b_out, ws);
  kattn_fused<<<256, 256, 0, stream>>>(enc, W_attn, b_attn, ws, out);
  ks2_logits_ctx<<<kStreamBlocks, 256, 0, stream>>>(W_out, ws);
  k8_lse_out<<<197, 256, 0, stream>>>(ws, out);
}